// Round 8
// baseline (655.322 us; speedup 1.0000x reference)
//
#include <hip/hip_runtime.h>

typedef _Float16 f16x8 __attribute__((ext_vector_type(8)));
typedef __fp16   half2 __attribute__((ext_vector_type(2)));
typedef float    f32x4 __attribute__((ext_vector_type(4)));

#define H_ 256
#define W_ 256

// ws byte offsets (linear; fragments read per-lane from L2 — kept hot by nt stores)
#define WS_W1S 0          // 64 rows x 32 f16 = 4096
#define WS_W2S 4096       // 2 chunks x 9 taps x 64 rows x 64B = 73728
#define WS_STG 77824      // Mws 32x128B=4096 | labs 64x64B=4096 | tn 128B

// LDS byte offsets (aliased, 32 KB peak -> 5 blocks/CU)
#define L_SX   0          // 1200 f32 = 4800
#define L_SQ1  4800       // 336 rows x 64B = 21504 (ends 26304)
#define L_SQ2  0          // 256 rows x 128B = 32768 (alias SX+SQ1, after conv2)
#define L_PT   0          // 256 rows x 64B = 16384 (alias SQ2, after distance)
#define LDS_SZ 32768

__global__ void repack_kernel(const float* __restrict__ w1, const float* __restrict__ b1,
                              const float* __restrict__ w2, const float* __restrict__ w3,
                              const float* __restrict__ b3, const float* __restrict__ mu,
                              const float* __restrict__ label, char* __restrict__ ws)
{
    int t = blockIdx.x * 256 + threadIdx.x;
    _Float16* w1s  = (_Float16*)(ws + WS_W1S);
    _Float16* w2l  = (_Float16*)(ws + WS_W2S);
    _Float16* mws  = (_Float16*)(ws + WS_STG);
    _Float16* labs = (_Float16*)(ws + WS_STG + 4096);
    float*    tn   = (float*)(ws + WS_STG + 8192);

    if (t < 2048) {            // w1s rows o: k<27 -> w1, k==27 -> b1, else 0
        int o = t >> 5, k = t & 31;
        float v = (k < 27) ? w1[o * 27 + k] : ((k == 27) ? b1[o] : 0.f);
        w1s[o * 32 + k] = (_Float16)v;
    }
    if (t < 36864) {           // w2[o][c][tap] -> [chunk][tap][row o][32 k], linear
        int n = t / 576, rem = t % 576, c = rem / 9, tap = rem % 9;
        int chunk = c >> 5, k = c & 31;
        w2l[((chunk * 9 + tap) * 64 + n) * 32 + k] = (_Float16)w2[t];
    }
    if (t < 2048) {            // Mw[n][c] = sum_o mu[n][o] w3[o][c], rows n x 64, linear
        int n = t >> 6, c = t & 63;
        float s = 0.f;
        for (int o = 0; o < 64; ++o) s += mu[n * 64 + o] * w3[o * 64 + c];
        mws[n * 64 + c] = (_Float16)s;
    }
    if (t < 2048) {            // label[o][n] rows o x 32, linear
        int o = t >> 5, cl = t & 31;
        labs[o * 32 + cl] = (_Float16)label[o * 32 + cl];
    }
    if (t < 32) {              // tn = 2*mu.b3 - ||mu||^2
        float d = 0.f, m2 = 0.f;
        for (int o = 0; o < 64; ++o) { float m = mu[t * 64 + o]; d += m * b3[o]; m2 += m * m; }
        tn[t] = 2.f * d - m2;
    }
}

__global__ __launch_bounds__(256, 5) void fused_kernel(
    const float* __restrict__ x, const char* __restrict__ ws,
    const float* __restrict__ b2, float* __restrict__ out)
{
    __shared__ __align__(16) char smem[LDS_SZ];
    const int tid = threadIdx.x;
    const int lane = tid & 63;
    const int wv = tid >> 6;
    const int ln = lane & 15;
    const int lg = lane >> 4;
    const int w0 = blockIdx.x * 16, h0 = blockIdx.y * 16, bz = blockIdx.z;

    // ---- phase 0: stage x tile only ----
    {
        float* sx = (float*)(smem + L_SX);
        for (int i = tid; i < 1200; i += 256) {
            int ci = i / 400, r = (i / 20) % 20, c = i % 20;
            int gy = min(max(h0 - 2 + r, 0), H_ - 1);
            int gx = min(max(w0 - 2 + c, 0), W_ - 1);
            sx[i] = x[((bz * 3 + ci) * H_ + gy) * W_ + gx];
        }
    }
    float b2v[4][4];
#pragma unroll
    for (int nb = 0; nb < 4; ++nb)
#pragma unroll
        for (int jr = 0; jr < 4; ++jr)
            b2v[nb][jr] = b2[nb * 16 + lg * 4 + jr];

    // conv1 im2col lane constants for k = lg*8+j
    int koff[8]; float kcv[8]; int kvalid[8];
#pragma unroll
    for (int j = 0; j < 8; ++j) {
        int k = lg * 8 + j;
        int ci = (k * 57) >> 9;          // k/9, valid k<27
        int r  = k - 9 * ci;
        int dy = (r * 22) >> 6;          // r/3
        int dx = r - 3 * dy;
        koff[j]   = ci * 400 + dy * 20 + dx;
        kvalid[j] = (k < 27);
        kcv[j]    = (k == 27) ? 1.0f : 0.0f;   // bias slot
    }

    __syncthreads();   // 1: sx ready

    const f16x8* w1sp = (const f16x8*)(ws + WS_W1S);
    const float* sxp = (const float*)(smem + L_SX);

    f32x4 acc[4][4];
#pragma unroll
    for (int i = 0; i < 4; ++i)
#pragma unroll
        for (int nb = 0; nb < 4; ++nb)
            acc[i][nb] = (f32x4){b2v[nb][0], b2v[nb][1], b2v[nb][2], b2v[nb][3]};

    f16x8 bfr[6];
    int wrow[6], wswp[6];

    // ---- conv1 pass 0 (channels 0..31): build im2col frags + MFMA + packed writes ----
    {
        f16x8 w1f[2];
#pragma unroll
        for (int nb2 = 0; nb2 < 2; ++nb2)
            w1f[nb2] = w1sp[(nb2 * 16 + ln) * 4 + lg];
#pragma unroll
        for (int t = 0; t < 6; ++t) {
            int pb = wv + 4 * t;
            if (pb >= 21) break;
            int pos_w = pb * 16 + ln;
            int pos = min(pos_w, 323);
            int sy = (pos * 3641) >> 16;             // pos/18
            int sp = pos - sy * 18;
            int by = min(max(h0 - 1 + sy, 0), H_ - 1) - (h0 - 1);
            int bx = min(max(w0 - 1 + sp, 0), W_ - 1) - (w0 - 1);
            int base = by * 20 + bx;
            float g[8];
#pragma unroll
            for (int j = 0; j < 8; ++j) {
                float v = sxp[base + koff[j]];
                g[j] = kvalid[j] ? v : kcv[j];
            }
            union { half2 h2[4]; f16x8 f; } u;
#pragma unroll
            for (int jj = 0; jj < 4; ++jj)
                u.h2[jj] = __builtin_amdgcn_cvt_pkrtz(g[2 * jj], g[2 * jj + 1]);
            bfr[t] = u.f;
            wrow[t] = pos_w * 64 + ((lg & 1) << 3);
            wswp[t] = (pos_w ^ (pos_w >> 2)) & 3;
#pragma unroll
            for (int nb2 = 0; nb2 < 2; ++nb2) {
                f32x4 c0 = {0.f, 0.f, 0.f, 0.f};
                c0 = __builtin_amdgcn_mfma_f32_16x16x32_f16(w1f[nb2], bfr[t], c0, 0, 0, 0);
                union { half2 h2[2]; uint2 u2; } pk;
                pk.h2[0] = __builtin_amdgcn_cvt_pkrtz(fmaxf(c0[0], 0.f), fmaxf(c0[1], 0.f));
                pk.h2[1] = __builtin_amdgcn_cvt_pkrtz(fmaxf(c0[2], 0.f), fmaxf(c0[3], 0.f));
                int s2 = 2 * nb2 + (lg >> 1);
                *(uint2*)(smem + L_SQ1 + wrow[t] + ((s2 ^ wswp[t]) << 4)) = pk.u2;
            }
        }
    }
    __syncthreads();   // 2: sq1 (ch 0..31) ready

    // ---- conv2 chunk 0 (weights direct from L2) ----
#pragma unroll
    for (int tap = 0; tap < 9; ++tap) {
        const int dy = tap / 3, dx = tap % 3;
        f16x8 wf[4], qf[4];
#pragma unroll
        for (int nb = 0; nb < 4; ++nb)
            wf[nb] = *(const f16x8*)(ws + WS_W2S + ((tap * 64 + nb * 16 + ln) << 6) + (lg << 4));
#pragma unroll
        for (int i = 0; i < 4; ++i) {
            int pos = (wv * 4 + i + dy) * 18 + ln + dx;
            int sw = (pos ^ (pos >> 2)) & 3;
            qf[i] = *(const f16x8*)(smem + L_SQ1 + (pos << 6) + ((lg ^ sw) << 4));
        }
#pragma unroll
        for (int i = 0; i < 4; ++i)
#pragma unroll
            for (int nb = 0; nb < 4; ++nb)
                acc[i][nb] = __builtin_amdgcn_mfma_f32_16x16x32_f16(wf[nb], qf[i], acc[i][nb], 0, 0, 0);
    }
    __syncthreads();   // 3: chunk-0 reads of sq1 done

    // ---- conv1 pass 1 (channels 32..63, reuse cached frags) ----
    {
        f16x8 w1f[2];
#pragma unroll
        for (int nb2 = 0; nb2 < 2; ++nb2)
            w1f[nb2] = w1sp[(32 + nb2 * 16 + ln) * 4 + lg];
#pragma unroll
        for (int t = 0; t < 6; ++t) {
            int pb = wv + 4 * t;
            if (pb >= 21) break;
#pragma unroll
            for (int nb2 = 0; nb2 < 2; ++nb2) {
                f32x4 c0 = {0.f, 0.f, 0.f, 0.f};
                c0 = __builtin_amdgcn_mfma_f32_16x16x32_f16(w1f[nb2], bfr[t], c0, 0, 0, 0);
                union { half2 h2[2]; uint2 u2; } pk;
                pk.h2[0] = __builtin_amdgcn_cvt_pkrtz(fmaxf(c0[0], 0.f), fmaxf(c0[1], 0.f));
                pk.h2[1] = __builtin_amdgcn_cvt_pkrtz(fmaxf(c0[2], 0.f), fmaxf(c0[3], 0.f));
                int s2 = 2 * nb2 + (lg >> 1);
                *(uint2*)(smem + L_SQ1 + wrow[t] + ((s2 ^ wswp[t]) << 4)) = pk.u2;
            }
        }
    }
    __syncthreads();   // 4: sq1 (ch 32..63) ready

    // ---- conv2 chunk 1 ----
#pragma unroll
    for (int tap = 0; tap < 9; ++tap) {
        const int dy = tap / 3, dx = tap % 3;
        f16x8 wf[4], qf[4];
#pragma unroll
        for (int nb = 0; nb < 4; ++nb)
            wf[nb] = *(const f16x8*)(ws + WS_W2S + 36864 + ((tap * 64 + nb * 16 + ln) << 6) + (lg << 4));
#pragma unroll
        for (int i = 0; i < 4; ++i) {
            int pos = (wv * 4 + i + dy) * 18 + ln + dx;
            int sw = (pos ^ (pos >> 2)) & 3;
            qf[i] = *(const f16x8*)(smem + L_SQ1 + (pos << 6) + ((lg ^ sw) << 4));
        }
#pragma unroll
        for (int i = 0; i < 4; ++i)
#pragma unroll
            for (int nb = 0; nb < 4; ++nb)
                acc[i][nb] = __builtin_amdgcn_mfma_f32_16x16x32_f16(wf[nb], qf[i], acc[i][nb], 0, 0, 0);
    }
    __syncthreads();   // 5: sq1/sx dead; SQ2 region free

    // ---- a = relu(conv2) -> sq2 [pixel][64ch], b64 packed writes ----
#pragma unroll
    for (int i = 0; i < 4; ++i) {
        int pix = (wv * 4 + i) * 16 + ln;
        int sw = pix & 7;
#pragma unroll
        for (int nb = 0; nb < 4; ++nb) {
            union { half2 h2[2]; uint2 u2; } pk;
            pk.h2[0] = __builtin_amdgcn_cvt_pkrtz(fmaxf(acc[i][nb][0], 0.f), fmaxf(acc[i][nb][1], 0.f));
            pk.h2[1] = __builtin_amdgcn_cvt_pkrtz(fmaxf(acc[i][nb][2], 0.f), fmaxf(acc[i][nb][3], 0.f));
            int s2 = 2 * nb + (lg >> 1);
            *(uint2*)(smem + L_SQ2 + (pix << 7) + ((s2 ^ sw) << 4) + ((lg & 1) << 3)) = pk.u2;
        }
    }
    __syncthreads();   // 6: sq2 ready

    // ---- distance GEMM: C[n][pixel] = Mw . a ; then in-lane softmax ----
    float tnr[8];
#pragma unroll
    for (int nb2 = 0; nb2 < 2; ++nb2)
#pragma unroll
        for (int jr = 0; jr < 4; ++jr)
            tnr[nb2 * 4 + jr] = *(const float*)(ws + WS_STG + 8192 + ((nb2 * 16 + lg * 4 + jr) << 2));

    f32x4 acc3[4][2];
#pragma unroll
    for (int i = 0; i < 4; ++i)
#pragma unroll
        for (int nb2 = 0; nb2 < 2; ++nb2) acc3[i][nb2] = (f32x4){0.f, 0.f, 0.f, 0.f};
#pragma unroll
    for (int ks = 0; ks < 2; ++ks) {
        f16x8 mwf[2], af[4];
#pragma unroll
        for (int nb2 = 0; nb2 < 2; ++nb2)
            mwf[nb2] = *(const f16x8*)(ws + WS_STG + ((nb2 * 16 + ln) << 7) + ((ks * 4 + lg) << 4));
#pragma unroll
        for (int i = 0; i < 4; ++i) {
            int pix = (wv * 4 + i) * 16 + ln;
            af[i] = *(const f16x8*)(smem + L_SQ2 + (pix << 7) + (((ks * 4 + lg) ^ (pix & 7)) << 4));
        }
#pragma unroll
        for (int i = 0; i < 4; ++i)
#pragma unroll
            for (int nb2 = 0; nb2 < 2; ++nb2)
                acc3[i][nb2] = __builtin_amdgcn_mfma_f32_16x16x32_f16(mwf[nb2], af[i], acc3[i][nb2], 0, 0, 0);
    }

    float pv[4][8];
#pragma unroll
    for (int i = 0; i < 4; ++i) {
        float l[8];
#pragma unroll
        for (int nb2 = 0; nb2 < 2; ++nb2)
#pragma unroll
            for (int jr = 0; jr < 4; ++jr)
                l[nb2 * 4 + jr] = 2.f * acc3[i][nb2][jr] + tnr[nb2 * 4 + jr];
        float mx = l[0];
#pragma unroll
        for (int j = 1; j < 8; ++j) mx = fmaxf(mx, l[j]);
        mx = fmaxf(mx, __shfl_xor(mx, 16));
        mx = fmaxf(mx, __shfl_xor(mx, 32));
        float ssum = 0.f;
#pragma unroll
        for (int j = 0; j < 8; ++j) { l[j] = __expf(l[j] - mx); ssum += l[j]; }
        ssum += __shfl_xor(ssum, 16);
        ssum += __shfl_xor(ssum, 32);
        float inv = 1.f / ssum;
#pragma unroll
        for (int j = 0; j < 8; ++j) pv[i][j] = l[j] * inv;
    }
    __syncthreads();   // 7: all distance reads of sq2 done; PT region free

#pragma unroll
    for (int i = 0; i < 4; ++i) {
        int pix = (wv * 4 + i) * 16 + ln;
        int sw = (pix ^ (pix >> 2)) & 3;
#pragma unroll
        for (int nb2 = 0; nb2 < 2; ++nb2) {
            union { half2 h2[2]; uint2 u2; } pk;
            pk.h2[0] = __builtin_amdgcn_cvt_pkrtz(pv[i][nb2 * 4 + 0], pv[i][nb2 * 4 + 1]);
            pk.h2[1] = __builtin_amdgcn_cvt_pkrtz(pv[i][nb2 * 4 + 2], pv[i][nb2 * 4 + 3]);
            int s2 = 2 * nb2 + (lg >> 1);
            *(uint2*)(smem + L_PT + (pix << 6) + ((s2 ^ sw) << 4) + ((lg & 1) << 3)) = pk.u2;
        }
    }
    __syncthreads();   // 8: p-tile ready

    // ---- label GEMM: C[o][pixel] = label . p ; coalesced NON-TEMPORAL stores ----
    f16x8 lf[4], pf[4];
#pragma unroll
    for (int nb = 0; nb < 4; ++nb)
        lf[nb] = *(const f16x8*)(ws + WS_STG + 4096 + ((nb * 16 + ln) << 6) + (lg << 4));
#pragma unroll
    for (int i = 0; i < 4; ++i) {
        int pix = (wv * 4 + i) * 16 + ln;
        int sw = (pix ^ (pix >> 2)) & 3;
        pf[i] = *(const f16x8*)(smem + L_PT + (pix << 6) + ((lg ^ sw) << 4));
    }
#pragma unroll
    for (int i = 0; i < 4; ++i) {
        int base = (bz * 64 * H_ + (h0 + wv * 4 + i)) * W_ + w0 + ln;
#pragma unroll
        for (int nb = 0; nb < 4; ++nb) {
            f32x4 c4 = {0.f, 0.f, 0.f, 0.f};
            c4 = __builtin_amdgcn_mfma_f32_16x16x32_f16(lf[nb], pf[i], c4, 0, 0, 0);
#pragma unroll
            for (int jr = 0; jr < 4; ++jr)
                __builtin_nontemporal_store(c4[jr], &out[base + (nb * 16 + lg * 4 + jr) * (H_ * W_)]);
        }
    }
}

extern "C" void kernel_launch(void* const* d_in, const int* in_sizes, int n_in,
                              void* d_out, int out_size, void* d_ws, size_t ws_size,
                              hipStream_t stream) {
    const float* x  = (const float*)d_in[0];
    const float* w1 = (const float*)d_in[1];
    const float* b1 = (const float*)d_in[2];
    const float* w2 = (const float*)d_in[3];
    const float* b2 = (const float*)d_in[4];
    const float* w3 = (const float*)d_in[5];
    const float* b3 = (const float*)d_in[6];
    const float* mu = (const float*)d_in[7];
    const float* lb = (const float*)d_in[8];
    float* out = (float*)d_out;
    char* ws = (char*)d_ws;

    repack_kernel<<<144, 256, 0, stream>>>(w1, b1, w2, w3, b3, mu, lb, ws);
    dim3 grid(W_ / 16, H_ / 16, 8);
    fused_kernel<<<grid, 256, 0, stream>>>(x, ws, b2, out);
}

// Round 9
// 120.522 us; speedup vs baseline: 5.4374x; 5.4374x over previous
//
#include <hip/hip_runtime.h>

typedef _Float16 f16x8 __attribute__((ext_vector_type(8)));
typedef __fp16   half2 __attribute__((ext_vector_type(2)));
typedef float    f32x4 __attribute__((ext_vector_type(4)));

#define H_ 256
#define W_ 256

// ws byte offsets
#define WS_W1S 0          // 64 rows x 32 f16 = 4096
#define WS_W2S 4096       // 2 chunks x 9 taps x 64 rows x 64B = 73728 (linear)
#define WS_STG 77824      // Mws 4096 (pre-swizzled) | labs 4096 (pre-swizzled) | tn 128
#define STG_U4 520        // 8320 B

// LDS byte offsets (peak 54336 -> 3 blocks/CU)
#define L_SQ1  0          // 324 rows x 64B = 20736 (writes guarded pos<324)
#define L_W2T  20736      // 5 taps x 64 rows x 64B = 20480 (one tap-group of one chunk)
#define L_SX   41216      // 1200 f32 = 4800
#define L_STG  46016      // 8320
#define L_SQ2  0          // 256 rows x 128B = 32768 (alias SQ1+W2T after conv2)
#define L_PT   0          // 256 rows x 64B = 16384 (alias SQ2 after distance)
#define LDS_SZ 54336

__global__ void repack_kernel(const float* __restrict__ w1, const float* __restrict__ b1,
                              const float* __restrict__ w2, const float* __restrict__ w3,
                              const float* __restrict__ b3, const float* __restrict__ mu,
                              const float* __restrict__ label, char* __restrict__ ws)
{
    int t = blockIdx.x * 256 + threadIdx.x;
    _Float16* w1s  = (_Float16*)(ws + WS_W1S);
    _Float16* w2l  = (_Float16*)(ws + WS_W2S);
    _Float16* mws  = (_Float16*)(ws + WS_STG);
    _Float16* labs = (_Float16*)(ws + WS_STG + 4096);
    float*    tn   = (float*)(ws + WS_STG + 8192);

    if (t < 2048) {            // w1s rows o: k<27 -> w1, k==27 -> b1, else 0
        int o = t >> 5, k = t & 31;
        float v = (k < 27) ? w1[o * 27 + k] : ((k == 27) ? b1[o] : 0.f);
        w1s[o * 32 + k] = (_Float16)v;
    }
    if (t < 36864) {           // w2[o][c][tap] -> [chunk][tap][row o][32 k], linear
        int n = t / 576, rem = t % 576, c = rem / 9, tap = rem % 9;
        int chunk = c >> 5, k = c & 31;
        w2l[((chunk * 9 + tap) * 64 + n) * 32 + k] = (_Float16)w2[t];
    }
    if (t < 2048) {            // Mw[n][c], rows n x 64, pre-swizzled for LDS frag reads
        int n = t >> 6, c = t & 63;
        float s = 0.f;
        for (int o = 0; o < 64; ++o) s += mu[n * 64 + o] * w3[o * 64 + c];
        int slot = (c >> 3) ^ (n & 7);
        mws[n * 64 + slot * 8 + (c & 7)] = (_Float16)s;
    }
    if (t < 2048) {            // label[o][n] rows o x 32, pre-swizzled
        int o = t >> 5, cl = t & 31;
        int slot = (cl >> 3) ^ ((o ^ (o >> 2)) & 3);
        labs[o * 32 + slot * 8 + (cl & 7)] = (_Float16)label[o * 32 + cl];
    }
    if (t < 32) {              // tn = 2*mu.b3 - ||mu||^2
        float d = 0.f, m2 = 0.f;
        for (int o = 0; o < 64; ++o) { float m = mu[t * 64 + o]; d += m * b3[o]; m2 += m * m; }
        tn[t] = 2.f * d - m2;
    }
}

// stage taps [t0, t0+NT) of one w2 chunk into L_W2T, swizzling slots for
// conflict-free conv2 fragment reads
template<int NT>
__device__ __forceinline__ void stage_w2(const char* ws, char* smem, int chunk_off, int t0, int tid) {
    const uint4* s = (const uint4*)(ws + WS_W2S + chunk_off + t0 * 64 * 64);
    for (int i = tid; i < NT * 256; i += 256) {
        int row = i >> 2;                      // (tap-t0)*64 + n
        int key = (row ^ (row >> 2)) & 3;      // == (n ^ (n>>2))&3
        *(uint4*)(smem + L_W2T + (row << 6) + (((i & 3) ^ key) << 4)) = s[i];
    }
}

template<int T0, int NT>
__device__ __forceinline__ void conv2_taps(const char* smem, f32x4 (&acc)[4][4],
                                           int wv, int ln, int lg, int swl) {
#pragma unroll
    for (int tt = 0; tt < NT; ++tt) {
        const int tap = T0 + tt;
        const int dy = tap / 3, dx = tap % 3;
        f16x8 wf[4], qf[4];
#pragma unroll
        for (int nb = 0; nb < 4; ++nb) {
            int n = nb * 16 + ln;
            wf[nb] = *(const f16x8*)(smem + L_W2T + ((tt * 64 + n) << 6) + ((lg ^ swl) << 4));
        }
#pragma unroll
        for (int i = 0; i < 4; ++i) {
            int pos = (wv * 4 + i + dy) * 18 + ln + dx;
            int sw = (pos ^ (pos >> 2)) & 3;
            qf[i] = *(const f16x8*)(smem + L_SQ1 + (pos << 6) + ((lg ^ sw) << 4));
        }
#pragma unroll
        for (int i = 0; i < 4; ++i)
#pragma unroll
            for (int nb = 0; nb < 4; ++nb)
                acc[i][nb] = __builtin_amdgcn_mfma_f32_16x16x32_f16(wf[nb], qf[i], acc[i][nb], 0, 0, 0);
    }
}

__global__ __launch_bounds__(256, 3) void fused_kernel(
    const float* __restrict__ x, const char* __restrict__ ws,
    const float* __restrict__ b2, float* __restrict__ out)
{
    __shared__ __align__(16) char smem[LDS_SZ];
    const int tid = threadIdx.x;
    const int lane = tid & 63;
    const int wv = tid >> 6;
    const int ln = lane & 15;
    const int lg = lane >> 4;
    const int swl = (ln ^ (ln >> 2)) & 3;
    const int w0 = blockIdx.x * 16, h0 = blockIdx.y * 16, bz = blockIdx.z;

    // ---- phase 0: stage STG consts + x tile + w2 chunk0 taps 0..4 ----
    {
        const uint4* s = (const uint4*)(ws + WS_STG);
        uint4* d = (uint4*)(smem + L_STG);
        for (int i = tid; i < STG_U4; i += 256) d[i] = s[i];
    }
    {
        float* sx = (float*)(smem + L_SX);
        for (int i = tid; i < 1200; i += 256) {
            int ci = i / 400, r = (i / 20) % 20, c = i % 20;
            int gy = min(max(h0 - 2 + r, 0), H_ - 1);
            int gx = min(max(w0 - 2 + c, 0), W_ - 1);
            sx[i] = x[((bz * 3 + ci) * H_ + gy) * W_ + gx];
        }
    }
    stage_w2<5>(ws, smem, 0, 0, tid);

    float b2v[4][4];
#pragma unroll
    for (int nb = 0; nb < 4; ++nb)
#pragma unroll
        for (int jr = 0; jr < 4; ++jr)
            b2v[nb][jr] = b2[nb * 16 + lg * 4 + jr];

    // conv1 im2col lane constants for k = lg*8+j
    int koff[8]; float kcv[8]; int kvalid[8];
#pragma unroll
    for (int j = 0; j < 8; ++j) {
        int k = lg * 8 + j;
        int ci = (k * 57) >> 9;          // k/9, valid k<27
        int r  = k - 9 * ci;
        int dy = (r * 22) >> 6;          // r/3
        int dx = r - 3 * dy;
        koff[j]   = ci * 400 + dy * 20 + dx;
        kvalid[j] = (k < 27);
        kcv[j]    = (k == 27) ? 1.0f : 0.0f;   // bias slot
    }

    __syncthreads();   // B1: sx + stg + w2 c0 t0-4 ready

    const f16x8* w1sp = (const f16x8*)(ws + WS_W1S);
    const float* sxp = (const float*)(smem + L_SX);

    f32x4 acc[4][4];
#pragma unroll
    for (int i = 0; i < 4; ++i)
#pragma unroll
        for (int nb = 0; nb < 4; ++nb)
            acc[i][nb] = (f32x4){b2v[nb][0], b2v[nb][1], b2v[nb][2], b2v[nb][3]};

    f16x8 bfr[6];
    int wrow[6], wswp[6], wok[6];

    // ---- conv1 pass 0 (channels 0..31) ----
    {
        f16x8 w1f[2];
#pragma unroll
        for (int nb2 = 0; nb2 < 2; ++nb2)
            w1f[nb2] = w1sp[(nb2 * 16 + ln) * 4 + lg];
#pragma unroll
        for (int t = 0; t < 6; ++t) {
            int pb = wv + 4 * t;
            if (pb >= 21) break;
            int pos_w = pb * 16 + ln;
            int pos = min(pos_w, 323);
            int sy = (pos * 3641) >> 16;             // pos/18
            int sp = pos - sy * 18;
            int by = min(max(h0 - 1 + sy, 0), H_ - 1) - (h0 - 1);
            int bx = min(max(w0 - 1 + sp, 0), W_ - 1) - (w0 - 1);
            int base = by * 20 + bx;
            float g[8];
#pragma unroll
            for (int j = 0; j < 8; ++j) {
                float v = sxp[base + koff[j]];
                g[j] = kvalid[j] ? v : kcv[j];
            }
            union { half2 h2[4]; f16x8 f; } u;
#pragma unroll
            for (int jj = 0; jj < 4; ++jj)
                u.h2[jj] = __builtin_amdgcn_cvt_pkrtz(g[2 * jj], g[2 * jj + 1]);
            bfr[t] = u.f;
            wrow[t] = pos_w * 64 + ((lg & 1) << 3);
            wswp[t] = (pos_w ^ (pos_w >> 2)) & 3;
            wok[t]  = (pos_w < 324);                 // rows >=324 would smash L_W2T
#pragma unroll
            for (int nb2 = 0; nb2 < 2; ++nb2) {
                f32x4 c0 = {0.f, 0.f, 0.f, 0.f};
                c0 = __builtin_amdgcn_mfma_f32_16x16x32_f16(w1f[nb2], bfr[t], c0, 0, 0, 0);
                union { half2 h2[2]; uint2 u2; } pk;
                pk.h2[0] = __builtin_amdgcn_cvt_pkrtz(fmaxf(c0[0], 0.f), fmaxf(c0[1], 0.f));
                pk.h2[1] = __builtin_amdgcn_cvt_pkrtz(fmaxf(c0[2], 0.f), fmaxf(c0[3], 0.f));
                int s2 = 2 * nb2 + (lg >> 1);
                if (wok[t])
                    *(uint2*)(smem + L_SQ1 + wrow[t] + ((s2 ^ wswp[t]) << 4)) = pk.u2;
            }
        }
    }
    __syncthreads();   // B2: sq1 (ch 0..31) ready

    conv2_taps<0, 5>(smem, acc, wv, ln, lg, swl);
    __syncthreads();   // B3: taps 0-4 reads done
    stage_w2<4>(ws, smem, 0, 5, tid);
    __syncthreads();   // B4: w2 c0 t5-8 ready
    conv2_taps<5, 4>(smem, acc, wv, ln, lg, swl);
    __syncthreads();   // B5: chunk-0 reads done

    // ---- conv1 pass 1 (channels 32..63, cached frags) + stage w2 c1 t0-4 ----
    stage_w2<5>(ws, smem, 36864, 0, tid);
    {
        f16x8 w1f[2];
#pragma unroll
        for (int nb2 = 0; nb2 < 2; ++nb2)
            w1f[nb2] = w1sp[(32 + nb2 * 16 + ln) * 4 + lg];
#pragma unroll
        for (int t = 0; t < 6; ++t) {
            int pb = wv + 4 * t;
            if (pb >= 21) break;
#pragma unroll
            for (int nb2 = 0; nb2 < 2; ++nb2) {
                f32x4 c0 = {0.f, 0.f, 0.f, 0.f};
                c0 = __builtin_amdgcn_mfma_f32_16x16x32_f16(w1f[nb2], bfr[t], c0, 0, 0, 0);
                union { half2 h2[2]; uint2 u2; } pk;
                pk.h2[0] = __builtin_amdgcn_cvt_pkrtz(fmaxf(c0[0], 0.f), fmaxf(c0[1], 0.f));
                pk.h2[1] = __builtin_amdgcn_cvt_pkrtz(fmaxf(c0[2], 0.f), fmaxf(c0[3], 0.f));
                int s2 = 2 * nb2 + (lg >> 1);
                if (wok[t])
                    *(uint2*)(smem + L_SQ1 + wrow[t] + ((s2 ^ wswp[t]) << 4)) = pk.u2;
            }
        }
    }
    __syncthreads();   // B6: sq1 (ch 32..63) + w2 c1 t0-4 ready

    conv2_taps<0, 5>(smem, acc, wv, ln, lg, swl);
    __syncthreads();   // B7: taps 0-4 reads done
    stage_w2<4>(ws, smem, 36864, 5, tid);
    __syncthreads();   // B8: w2 c1 t5-8 ready
    conv2_taps<5, 4>(smem, acc, wv, ln, lg, swl);
    __syncthreads();   // B9: all conv2 reads done; SQ2 region free

    // ---- a = relu(conv2) -> sq2 [pixel][64ch], b64 packed writes ----
#pragma unroll
    for (int i = 0; i < 4; ++i) {
        int pix = (wv * 4 + i) * 16 + ln;
        int sw = pix & 7;
#pragma unroll
        for (int nb = 0; nb < 4; ++nb) {
            union { half2 h2[2]; uint2 u2; } pk;
            pk.h2[0] = __builtin_amdgcn_cvt_pkrtz(fmaxf(acc[i][nb][0], 0.f), fmaxf(acc[i][nb][1], 0.f));
            pk.h2[1] = __builtin_amdgcn_cvt_pkrtz(fmaxf(acc[i][nb][2], 0.f), fmaxf(acc[i][nb][3], 0.f));
            int s2 = 2 * nb + (lg >> 1);
            *(uint2*)(smem + L_SQ2 + (pix << 7) + ((s2 ^ sw) << 4) + ((lg & 1) << 3)) = pk.u2;
        }
    }
    __syncthreads();   // B10: sq2 ready

    // ---- distance GEMM: C[n][pixel] = Mw . a ; then in-lane softmax ----
    float tnr[8];
#pragma unroll
    for (int nb2 = 0; nb2 < 2; ++nb2)
#pragma unroll
        for (int jr = 0; jr < 4; ++jr)
            tnr[nb2 * 4 + jr] = *(const float*)(smem + L_STG + 8192 + ((nb2 * 16 + lg * 4 + jr) << 2));

    f32x4 acc3[4][2];
#pragma unroll
    for (int i = 0; i < 4; ++i)
#pragma unroll
        for (int nb2 = 0; nb2 < 2; ++nb2) acc3[i][nb2] = (f32x4){0.f, 0.f, 0.f, 0.f};
#pragma unroll
    for (int ks = 0; ks < 2; ++ks) {
        f16x8 mwf[2], af[4];
#pragma unroll
        for (int nb2 = 0; nb2 < 2; ++nb2)
            mwf[nb2] = *(const f16x8*)(smem + L_STG + ((nb2 * 16 + ln) << 7) + (((ks * 4 + lg) ^ (ln & 7)) << 4));
#pragma unroll
        for (int i = 0; i < 4; ++i) {
            int pix = (wv * 4 + i) * 16 + ln;
            af[i] = *(const f16x8*)(smem + L_SQ2 + (pix << 7) + (((ks * 4 + lg) ^ (pix & 7)) << 4));
        }
#pragma unroll
        for (int i = 0; i < 4; ++i)
#pragma unroll
            for (int nb2 = 0; nb2 < 2; ++nb2)
                acc3[i][nb2] = __builtin_amdgcn_mfma_f32_16x16x32_f16(mwf[nb2], af[i], acc3[i][nb2], 0, 0, 0);
    }

    float pv[4][8];
#pragma unroll
    for (int i = 0; i < 4; ++i) {
        float l[8];
#pragma unroll
        for (int nb2 = 0; nb2 < 2; ++nb2)
#pragma unroll
            for (int jr = 0; jr < 4; ++jr)
                l[nb2 * 4 + jr] = 2.f * acc3[i][nb2][jr] + tnr[nb2 * 4 + jr];
        float mx = l[0];
#pragma unroll
        for (int j = 1; j < 8; ++j) mx = fmaxf(mx, l[j]);
        mx = fmaxf(mx, __shfl_xor(mx, 16));
        mx = fmaxf(mx, __shfl_xor(mx, 32));
        float ssum = 0.f;
#pragma unroll
        for (int j = 0; j < 8; ++j) { l[j] = __expf(l[j] - mx); ssum += l[j]; }
        ssum += __shfl_xor(ssum, 16);
        ssum += __shfl_xor(ssum, 32);
        float inv = 1.f / ssum;
#pragma unroll
        for (int j = 0; j < 8; ++j) pv[i][j] = l[j] * inv;
    }
    __syncthreads();   // B11: distance reads of sq2 done; PT region free

#pragma unroll
    for (int i = 0; i < 4; ++i) {
        int pix = (wv * 4 + i) * 16 + ln;
        int sw = (pix ^ (pix >> 2)) & 3;
#pragma unroll
        for (int nb2 = 0; nb2 < 2; ++nb2) {
            union { half2 h2[2]; uint2 u2; } pk;
            pk.h2[0] = __builtin_amdgcn_cvt_pkrtz(pv[i][nb2 * 4 + 0], pv[i][nb2 * 4 + 1]);
            pk.h2[1] = __builtin_amdgcn_cvt_pkrtz(pv[i][nb2 * 4 + 2], pv[i][nb2 * 4 + 3]);
            int s2 = 2 * nb2 + (lg >> 1);
            *(uint2*)(smem + L_PT + (pix << 6) + ((s2 ^ sw) << 4) + ((lg & 1) << 3)) = pk.u2;
        }
    }
    __syncthreads();   // B12: p-tile ready

    // ---- label GEMM: C[o][pixel] = label . p ; coalesced stores (normal, L2-merged) ----
    f16x8 lf[4], pf[4];
#pragma unroll
    for (int nb = 0; nb < 4; ++nb)
        lf[nb] = *(const f16x8*)(smem + L_STG + 4096 + ((nb * 16 + ln) << 6) + ((lg ^ swl) << 4));
#pragma unroll
    for (int i = 0; i < 4; ++i) {
        int pix = (wv * 4 + i) * 16 + ln;
        int sw = (pix ^ (pix >> 2)) & 3;
        pf[i] = *(const f16x8*)(smem + L_PT + (pix << 6) + ((lg ^ sw) << 4));
    }
#pragma unroll
    for (int i = 0; i < 4; ++i) {
        int base = (bz * 64 * H_ + (h0 + wv * 4 + i)) * W_ + w0 + ln;
#pragma unroll
        for (int nb = 0; nb < 4; ++nb) {
            f32x4 c4 = {0.f, 0.f, 0.f, 0.f};
            c4 = __builtin_amdgcn_mfma_f32_16x16x32_f16(lf[nb], pf[i], c4, 0, 0, 0);
#pragma unroll
            for (int jr = 0; jr < 4; ++jr)
                out[base + (nb * 16 + lg * 4 + jr) * (H_ * W_)] = c4[jr];
        }
    }
}

extern "C" void kernel_launch(void* const* d_in, const int* in_sizes, int n_in,
                              void* d_out, int out_size, void* d_ws, size_t ws_size,
                              hipStream_t stream) {
    const float* x  = (const float*)d_in[0];
    const float* w1 = (const float*)d_in[1];
    const float* b1 = (const float*)d_in[2];
    const float* w2 = (const float*)d_in[3];
    const float* b2 = (const float*)d_in[4];
    const float* w3 = (const float*)d_in[5];
    const float* b3 = (const float*)d_in[6];
    const float* mu = (const float*)d_in[7];
    const float* lb = (const float*)d_in[8];
    float* out = (float*)d_out;
    char* ws = (char*)d_ws;

    repack_kernel<<<144, 256, 0, stream>>>(w1, b1, w2, w3, b3, mu, lb, ws);
    dim3 grid(W_ / 16, H_ / 16, 8);
    fused_kernel<<<grid, 256, 0, stream>>>(x, ws, b2, out);
}

// Round 10
// 82.334 us; speedup vs baseline: 7.9593x; 1.4638x over previous
//
#include <hip/hip_runtime.h>

typedef _Float16 f16x8 __attribute__((ext_vector_type(8)));
typedef __fp16   half2 __attribute__((ext_vector_type(2)));
typedef float    f32x4 __attribute__((ext_vector_type(4)));

#define H_ 256
#define W_ 256

// ws byte offsets
#define WS_W1S 0          // 64 rows x 32 f16 (k=ci*9+tap; k27=bias, 28..31=0) = 4096
#define WS_W2S 4096       // 2 chunks x 9 taps x 64 rows x 64B = 73728
#define WS_STG 77824      // Mws 4096 | labs 4096 | tn 128
#define STG_U4 520        // 8320 B

// LDS byte offsets (71488 -> 2 blocks/CU; proven R4 layout)
#define L_SX   0          // 1200 f32 = 4800
#define L_SQ1  4800       // 336 rows x 64B = 21504 (ends 26304)
#define L_W2S  26304      // 36864 (one chunk, ends 63168)
#define L_STG  63168      // 8320 (ends 71488)
#define L_SQ2  26304      // 256 rows x 128B = 32768 (aliases W2S after conv2)
                          // p-tile lives INSIDE each wave's own sq2 8KB sub-region
#define LDS_SZ 71488

__global__ void repack_kernel(const float* __restrict__ w1, const float* __restrict__ b1,
                              const float* __restrict__ w2, const float* __restrict__ w3,
                              const float* __restrict__ b3, const float* __restrict__ mu,
                              const float* __restrict__ label, char* __restrict__ ws)
{
    int t = blockIdx.x * 256 + threadIdx.x;
    _Float16* w1s  = (_Float16*)(ws + WS_W1S);
    _Float16* w2s  = (_Float16*)(ws + WS_W2S);
    _Float16* mws  = (_Float16*)(ws + WS_STG);
    _Float16* labs = (_Float16*)(ws + WS_STG + 4096);
    float*    tn   = (float*)(ws + WS_STG + 8192);

    if (t < 2048) {            // w1s rows o: k<27 -> w1, k==27 -> b1, else 0 (linear)
        int o = t >> 5, k = t & 31;
        float v = (k < 27) ? w1[o * 27 + k] : ((k == 27) ? b1[o] : 0.f);
        w1s[o * 32 + k] = (_Float16)v;
    }
    if (t < 36864) {           // w2[o][c][tap] -> [chunk][tap][row o][32 k], swizzled
        int n = t / 576, rem = t % 576, c = rem / 9, tap = rem % 9;
        int chunk = c >> 5, k = c & 31;
        int slot = (k >> 3) ^ ((n ^ (n >> 2)) & 3);
        w2s[((chunk * 9 + tap) * 64 + n) * 32 + slot * 8 + (k & 7)] = (_Float16)w2[t];
    }
    if (t < 2048) {            // Mw[n][c] = sum_o mu[n][o] w3[o][c], rows n x 64, swizzled
        int n = t >> 6, c = t & 63;
        float s = 0.f;
        for (int o = 0; o < 64; ++o) s += mu[n * 64 + o] * w3[o * 64 + c];
        int slot = (c >> 3) ^ (n & 7);
        mws[n * 64 + slot * 8 + (c & 7)] = (_Float16)s;
    }
    if (t < 2048) {            // label[o][n] rows o x 32, swizzled
        int o = t >> 5, cl = t & 31;
        int slot = (cl >> 3) ^ ((o ^ (o >> 2)) & 3);
        labs[o * 32 + slot * 8 + (cl & 7)] = (_Float16)label[o * 32 + cl];
    }
    if (t < 32) {              // tn = 2*mu.b3 - ||mu||^2
        float d = 0.f, m2 = 0.f;
        for (int o = 0; o < 64; ++o) { float m = mu[t * 64 + o]; d += m * b3[o]; m2 += m * m; }
        tn[t] = 2.f * d - m2;
    }
}

__global__ __launch_bounds__(256, 2) void fused_kernel(
    const float* __restrict__ x, const char* __restrict__ ws,
    const float* __restrict__ b2, float* __restrict__ out)
{
    __shared__ __align__(16) char smem[LDS_SZ];
    const int tid = threadIdx.x;
    const int lane = tid & 63;
    const int wv = tid >> 6;
    const int ln = lane & 15;
    const int lg = lane >> 4;
    const int swl = (ln ^ (ln >> 2)) & 3;
    const int ln7 = ln & 7;
    const int w0 = blockIdx.x * 16, h0 = blockIdx.y * 16, bz = blockIdx.z;

    // ---- phase 0: stage consts + w2s chunk0 + x tile ----
    {
        const uint4* s = (const uint4*)(ws + WS_STG);
        uint4* d = (uint4*)(smem + L_STG);
        for (int i = tid; i < STG_U4; i += 256) d[i] = s[i];
    }
    {
        const uint4* s = (const uint4*)(ws + WS_W2S);
        uint4* d = (uint4*)(smem + L_W2S);
        for (int i = tid; i < 2304; i += 256) d[i] = s[i];
    }
    {
        float* sx = (float*)(smem + L_SX);
        for (int i = tid; i < 1200; i += 256) {
            int ci = i / 400, r = (i / 20) % 20, c = i % 20;
            int gy = min(max(h0 - 2 + r, 0), H_ - 1);
            int gx = min(max(w0 - 2 + c, 0), W_ - 1);
            sx[i] = x[((bz * 3 + ci) * H_ + gy) * W_ + gx];
        }
    }
    float b2v[4][4];
#pragma unroll
    for (int nb = 0; nb < 4; ++nb)
#pragma unroll
        for (int jr = 0; jr < 4; ++jr)
            b2v[nb][jr] = b2[nb * 16 + lg * 4 + jr];

    // conv1 im2col lane constants for k = lg*8+j
    int koff[8]; float kcv[8]; int kvalid[8];
#pragma unroll
    for (int j = 0; j < 8; ++j) {
        int k = lg * 8 + j;
        int ci = (k * 57) >> 9;          // k/9, valid k<27
        int r  = k - 9 * ci;
        int dy = (r * 22) >> 6;          // r/3
        int dx = r - 3 * dy;
        koff[j]   = ci * 400 + dy * 20 + dx;
        kvalid[j] = (k < 27);
        kcv[j]    = (k == 27) ? 1.0f : 0.0f;   // bias slot
    }

    __syncthreads();   // B1: sx + stg + w2c0 ready

    const f16x8* w1sp = (const f16x8*)(ws + WS_W1S);
    const float* sxp = (const float*)(smem + L_SX);

    f32x4 acc[4][4];
#pragma unroll
    for (int i = 0; i < 4; ++i)
#pragma unroll
        for (int nb = 0; nb < 4; ++nb)
            acc[i][nb] = (f32x4){b2v[nb][0], b2v[nb][1], b2v[nb][2], b2v[nb][3]};

    f16x8 bfr[6];
    int wrow[6], wswp[6];

    // ---- conv1 pass 0 (channels 0..31): build im2col frags + MFMA + packed writes ----
    {
        f16x8 w1f[2];
#pragma unroll
        for (int nb2 = 0; nb2 < 2; ++nb2)
            w1f[nb2] = w1sp[(nb2 * 16 + ln) * 4 + lg];
#pragma unroll
        for (int t = 0; t < 6; ++t) {
            int pb = wv + 4 * t;
            if (pb >= 21) break;
            int pos_w = pb * 16 + ln;
            int pos = min(pos_w, 323);
            int sy = (pos * 3641) >> 16;             // pos/18
            int sp = pos - sy * 18;
            int by = min(max(h0 - 1 + sy, 0), H_ - 1) - (h0 - 1);
            int bx = min(max(w0 - 1 + sp, 0), W_ - 1) - (w0 - 1);
            int base = by * 20 + bx;
            float g[8];
#pragma unroll
            for (int j = 0; j < 8; ++j) {
                float v = sxp[base + koff[j]];
                g[j] = kvalid[j] ? v : kcv[j];
            }
            union { half2 h2[4]; f16x8 f; } u;
#pragma unroll
            for (int jj = 0; jj < 4; ++jj)
                u.h2[jj] = __builtin_amdgcn_cvt_pkrtz(g[2 * jj], g[2 * jj + 1]);
            bfr[t] = u.f;
            wrow[t] = pos_w * 64 + ((lg & 1) << 3);
            wswp[t] = (pos_w ^ (pos_w >> 2)) & 3;
#pragma unroll
            for (int nb2 = 0; nb2 < 2; ++nb2) {
                f32x4 c0 = {0.f, 0.f, 0.f, 0.f};
                c0 = __builtin_amdgcn_mfma_f32_16x16x32_f16(w1f[nb2], bfr[t], c0, 0, 0, 0);
                union { half2 h2[2]; uint2 u2; } pk;
                pk.h2[0] = __builtin_amdgcn_cvt_pkrtz(fmaxf(c0[0], 0.f), fmaxf(c0[1], 0.f));
                pk.h2[1] = __builtin_amdgcn_cvt_pkrtz(fmaxf(c0[2], 0.f), fmaxf(c0[3], 0.f));
                int s2 = 2 * nb2 + (lg >> 1);
                *(uint2*)(smem + L_SQ1 + wrow[t] + ((s2 ^ wswp[t]) << 4)) = pk.u2;
            }
        }
    }
    __syncthreads();   // B2: sq1 (ch 0..31) ready

    // ---- conv2 chunk 0 ----
#pragma unroll
    for (int tap = 0; tap < 9; ++tap) {
        const int dy = tap / 3, dx = tap % 3;
        f16x8 wf[4], qf[4];
#pragma unroll
        for (int nb = 0; nb < 4; ++nb)
            wf[nb] = *(const f16x8*)(smem + L_W2S + ((tap * 64 + nb * 16 + ln) << 6) + ((lg ^ swl) << 4));
#pragma unroll
        for (int i = 0; i < 4; ++i) {
            int pos = (wv * 4 + i + dy) * 18 + ln + dx;
            int sw = (pos ^ (pos >> 2)) & 3;
            qf[i] = *(const f16x8*)(smem + L_SQ1 + (pos << 6) + ((lg ^ sw) << 4));
        }
#pragma unroll
        for (int i = 0; i < 4; ++i)
#pragma unroll
            for (int nb = 0; nb < 4; ++nb)
                acc[i][nb] = __builtin_amdgcn_mfma_f32_16x16x32_f16(wf[nb], qf[i], acc[i][nb], 0, 0, 0);
    }
    __syncthreads();   // B3: conv2c0 reads of sq1/w2s done

    // ---- conv1 pass 1 (channels 32..63, cached frags) + stage w2s chunk1 ----
    {
        const uint4* s = (const uint4*)(ws + WS_W2S + 36864);
        uint4* d = (uint4*)(smem + L_W2S);
        for (int i = tid; i < 2304; i += 256) d[i] = s[i];
    }
    {
        f16x8 w1f[2];
#pragma unroll
        for (int nb2 = 0; nb2 < 2; ++nb2)
            w1f[nb2] = w1sp[(32 + nb2 * 16 + ln) * 4 + lg];
#pragma unroll
        for (int t = 0; t < 6; ++t) {
            int pb = wv + 4 * t;
            if (pb >= 21) break;
#pragma unroll
            for (int nb2 = 0; nb2 < 2; ++nb2) {
                f32x4 c0 = {0.f, 0.f, 0.f, 0.f};
                c0 = __builtin_amdgcn_mfma_f32_16x16x32_f16(w1f[nb2], bfr[t], c0, 0, 0, 0);
                union { half2 h2[2]; uint2 u2; } pk;
                pk.h2[0] = __builtin_amdgcn_cvt_pkrtz(fmaxf(c0[0], 0.f), fmaxf(c0[1], 0.f));
                pk.h2[1] = __builtin_amdgcn_cvt_pkrtz(fmaxf(c0[2], 0.f), fmaxf(c0[3], 0.f));
                int s2 = 2 * nb2 + (lg >> 1);
                *(uint2*)(smem + L_SQ1 + wrow[t] + ((s2 ^ wswp[t]) << 4)) = pk.u2;
            }
        }
    }
    __syncthreads();   // B4: sq1 (ch 32..63) + w2c1 ready

    // ---- conv2 chunk 1 ----
#pragma unroll
    for (int tap = 0; tap < 9; ++tap) {
        const int dy = tap / 3, dx = tap % 3;
        f16x8 wf[4], qf[4];
#pragma unroll
        for (int nb = 0; nb < 4; ++nb)
            wf[nb] = *(const f16x8*)(smem + L_W2S + ((tap * 64 + nb * 16 + ln) << 6) + ((lg ^ swl) << 4));
#pragma unroll
        for (int i = 0; i < 4; ++i) {
            int pos = (wv * 4 + i + dy) * 18 + ln + dx;
            int sw = (pos ^ (pos >> 2)) & 3;
            qf[i] = *(const f16x8*)(smem + L_SQ1 + (pos << 6) + ((lg ^ sw) << 4));
        }
#pragma unroll
        for (int i = 0; i < 4; ++i)
#pragma unroll
            for (int nb = 0; nb < 4; ++nb)
                acc[i][nb] = __builtin_amdgcn_mfma_f32_16x16x32_f16(wf[nb], qf[i], acc[i][nb], 0, 0, 0);
    }
    __syncthreads();   // B5: all conv2 reads done; sq2 region (aliases sq1+w2s) free
    // ======== TAIL: all producer/consumer pairs below are wave-private ========

    // ---- a = relu(conv2) -> sq2 [pixel][64ch], b64 packed writes (own rows) ----
#pragma unroll
    for (int i = 0; i < 4; ++i) {
        int pix = (wv * 4 + i) * 16 + ln;
        int sw = pix & 7;
#pragma unroll
        for (int nb = 0; nb < 4; ++nb) {
            union { half2 h2[2]; uint2 u2; } pk;
            pk.h2[0] = __builtin_amdgcn_cvt_pkrtz(fmaxf(acc[i][nb][0], 0.f), fmaxf(acc[i][nb][1], 0.f));
            pk.h2[1] = __builtin_amdgcn_cvt_pkrtz(fmaxf(acc[i][nb][2], 0.f), fmaxf(acc[i][nb][3], 0.f));
            int s2 = 2 * nb + (lg >> 1);
            *(uint2*)(smem + L_SQ2 + (pix << 7) + ((s2 ^ sw) << 4) + ((lg & 1) << 3)) = pk.u2;
        }
    }
    // (no barrier: each wave reads back only its own rows)

    // ---- distance GEMM: C[n][pixel] = Mw . a ; then in-lane softmax ----
    float tnr[8];
#pragma unroll
    for (int nb2 = 0; nb2 < 2; ++nb2)
#pragma unroll
        for (int jr = 0; jr < 4; ++jr)
            tnr[nb2 * 4 + jr] = *(const float*)(smem + L_STG + 8192 + ((nb2 * 16 + lg * 4 + jr) << 2));

    f32x4 acc3[4][2];
#pragma unroll
    for (int i = 0; i < 4; ++i)
#pragma unroll
        for (int nb2 = 0; nb2 < 2; ++nb2) acc3[i][nb2] = (f32x4){0.f, 0.f, 0.f, 0.f};
#pragma unroll
    for (int ks = 0; ks < 2; ++ks) {
        f16x8 mwf[2], af[4];
#pragma unroll
        for (int nb2 = 0; nb2 < 2; ++nb2)
            mwf[nb2] = *(const f16x8*)(smem + L_STG + ((nb2 * 16 + ln) << 7) + (((ks * 4 + lg) ^ ln7) << 4));
#pragma unroll
        for (int i = 0; i < 4; ++i) {
            int pix = (wv * 4 + i) * 16 + ln;
            af[i] = *(const f16x8*)(smem + L_SQ2 + (pix << 7) + (((ks * 4 + lg) ^ (pix & 7)) << 4));
        }
#pragma unroll
        for (int i = 0; i < 4; ++i)
#pragma unroll
            for (int nb2 = 0; nb2 < 2; ++nb2)
                acc3[i][nb2] = __builtin_amdgcn_mfma_f32_16x16x32_f16(mwf[nb2], af[i], acc3[i][nb2], 0, 0, 0);
    }

#pragma unroll
    for (int i = 0; i < 4; ++i) {
        float l[8];
#pragma unroll
        for (int nb2 = 0; nb2 < 2; ++nb2)
#pragma unroll
            for (int jr = 0; jr < 4; ++jr)
                l[nb2 * 4 + jr] = 2.f * acc3[i][nb2][jr] + tnr[nb2 * 4 + jr];
        float mx = l[0];
#pragma unroll
        for (int j = 1; j < 8; ++j) mx = fmaxf(mx, l[j]);
        mx = fmaxf(mx, __shfl_xor(mx, 16));
        mx = fmaxf(mx, __shfl_xor(mx, 32));
        float ssum = 0.f;
#pragma unroll
        for (int j = 0; j < 8; ++j) { l[j] = __expf(l[j] - mx); ssum += l[j]; }
        ssum += __shfl_xor(ssum, 16);
        ssum += __shfl_xor(ssum, 32);
        float inv = 1.f / ssum;
        // write attention p (fp16) into the wave's OWN sq2 sub-region (rows lr x 64B)
        int lr = i * 16 + ln;
        int pix = wv * 64 + lr;
        int sw = (pix ^ (pix >> 2)) & 3;
#pragma unroll
        for (int nb2 = 0; nb2 < 2; ++nb2) {
            union { half2 h2[2]; uint2 u2; } pk;
            pk.h2[0] = __builtin_amdgcn_cvt_pkrtz(l[nb2 * 4 + 0] * inv, l[nb2 * 4 + 1] * inv);
            pk.h2[1] = __builtin_amdgcn_cvt_pkrtz(l[nb2 * 4 + 2] * inv, l[nb2 * 4 + 3] * inv);
            int s2 = 2 * nb2 + (lg >> 1);
            *(uint2*)(smem + L_SQ2 + (wv << 13) + (lr << 6) + ((s2 ^ sw) << 4) + ((lg & 1) << 3)) = pk.u2;
        }
    }
    // (no barrier: p rows are wave-private, and they overwrite only this wave's
    //  own sq2 rows, all of which were already consumed by the distance GEMM)

    // ---- label GEMM: C[o][pixel] = label . p ; coalesced stores ----
    f16x8 lf[4], pf[4];
#pragma unroll
    for (int nb = 0; nb < 4; ++nb)
        lf[nb] = *(const f16x8*)(smem + L_STG + 4096 + ((nb * 16 + ln) << 6) + ((lg ^ swl) << 4));
#pragma unroll
    for (int i = 0; i < 4; ++i) {
        int lr = i * 16 + ln;
        int pix = wv * 64 + lr;
        int sw = (pix ^ (pix >> 2)) & 3;
        pf[i] = *(const f16x8*)(smem + L_SQ2 + (wv << 13) + (lr << 6) + ((lg ^ sw) << 4));
    }
#pragma unroll
    for (int i = 0; i < 4; ++i) {
        int base = (bz * 64 * H_ + (h0 + wv * 4 + i)) * W_ + w0 + ln;
#pragma unroll
        for (int nb = 0; nb < 4; ++nb) {
            f32x4 c4 = {0.f, 0.f, 0.f, 0.f};
            c4 = __builtin_amdgcn_mfma_f32_16x16x32_f16(lf[nb], pf[i], c4, 0, 0, 0);
#pragma unroll
            for (int jr = 0; jr < 4; ++jr)
                out[base + (nb * 16 + lg * 4 + jr) * (H_ * W_)] = c4[jr];
        }
    }
}

extern "C" void kernel_launch(void* const* d_in, const int* in_sizes, int n_in,
                              void* d_out, int out_size, void* d_ws, size_t ws_size,
                              hipStream_t stream) {
    const float* x  = (const float*)d_in[0];
    const float* w1 = (const float*)d_in[1];
    const float* b1 = (const float*)d_in[2];
    const float* w2 = (const float*)d_in[3];
    const float* b2 = (const float*)d_in[4];
    const float* w3 = (const float*)d_in[5];
    const float* b3 = (const float*)d_in[6];
    const float* mu = (const float*)d_in[7];
    const float* lb = (const float*)d_in[8];
    float* out = (float*)d_out;
    char* ws = (char*)d_ws;

    repack_kernel<<<144, 256, 0, stream>>>(w1, b1, w2, w3, b3, mu, lb, ws);
    dim3 grid(W_ / 16, H_ / 16, 8);
    fused_kernel<<<grid, 256, 0, stream>>>(x, ws, b2, out);
}